// Round 19
// baseline (208.439 us; speedup 1.0000x reference)
//
#include <hip/hip_runtime.h>
#include <hip/hip_bf16.h>
#include <math.h>

#define CH 64
#define NPOS 9216   // 96*96
#define NTOT 18432  // 2*9216
#define NSPLIT 8
#define TILES_PER_SPLIT 18   // 144/8
#define LOG2E 1.4426950408889634f

typedef short bf16x8 __attribute__((ext_vector_type(8)));
typedef short bf16x4 __attribute__((ext_vector_type(4)));
typedef float f32x4 __attribute__((ext_vector_type(4)));
typedef int   i32x4 __attribute__((ext_vector_type(4)));
typedef unsigned int u32;

__device__ __forceinline__ float bf2f(short s) {
  unsigned int u = ((unsigned int)(unsigned short)s) << 16;
  return __builtin_bit_cast(float, u);
}
__device__ __forceinline__ short f2bf(float f) {
  unsigned int u = __builtin_bit_cast(unsigned int, f);
  unsigned int r = (u + 0x7fffu + ((u >> 16) & 1u)) >> 16;  // RNE
  return (short)r;
}
__device__ __forceinline__ float gelu_exact(float x) {
  return 0.5f * x * (1.f + erff(x * 0.70710678118654752440f));
}

// R18: attn plateaued at 75us (frozen). Tail (~131us) hides in latency-starved
// kernels: k_fft had 288 waves (0.28/SIMD), k_ln_qkv 1.7/SIMD. R19: k_fft
// lane-cooperative (8 lanes/patch-ch via __shfl, 2304 waves); A z-split 2->8.

// ---------------- Kernel A: LN1 + QKV projection ----------------
// grid (72, 3, 8) x 256. og = 8-out-channel slice. Q/K -> [n][c]; V -> [c][n].
__global__ __launch_bounds__(256) void k_ln_qkv(
    const float* __restrict__ x, const float* __restrict__ ln1w, const float* __restrict__ ln1b,
    const float* __restrict__ qw, const float* __restrict__ qb,
    const float* __restrict__ kw, const float* __restrict__ kb,
    const float* __restrict__ vw, const float* __restrict__ vb,
    short* __restrict__ Qg, short* __restrict__ Kg, short* __restrict__ Vgt) {
  int mat = blockIdx.y;
  int og = blockIdx.z;
  const float* wsrc = (mat == 0) ? qw : (mat == 1) ? kw : vw;
  const float* bsrc = (mat == 0) ? qb : (mat == 1) ? kb : vb;
  int idx = blockIdx.x * 256 + threadIdx.x;
  int b = idx / NPOS, n = idx % NPOS;
  const float* xb = x + (size_t)b * CH * NPOS + n;
  float xr[64];
  float mu = 0.f;
#pragma unroll
  for (int c = 0; c < 64; ++c) { float v = xb[c * NPOS]; xr[c] = v; mu += v; }
  mu *= (1.f / 64.f);
  float var = 0.f;
#pragma unroll
  for (int c = 0; c < 64; ++c) { float d = xr[c] - mu; var += d * d; }
  float rstd = rsqrtf(var * (1.f / 64.f) + 1e-5f);
#pragma unroll
  for (int c = 0; c < 64; ++c) xr[c] = (xr[c] - mu) * rstd * ln1w[c] + ln1b[c];
  if (mat == 2) {
#pragma unroll
    for (int j = 0; j < 8; ++j) {
      int o = og * 8 + j;
      float acc = bsrc[o];
      const float* wrow = wsrc + o * 64;
#pragma unroll
      for (int c = 0; c < 64; ++c) acc += wrow[c] * xr[c];
      Vgt[(size_t)o * NTOT + idx] = f2bf(acc);
    }
  } else {
    float kscale = (mat == 1) ? LOG2E : 1.f;
    short* outp = ((mat == 0) ? Qg : Kg) + (size_t)idx * 64 + og * 8;
    bf16x8 v8;
#pragma unroll
    for (int j = 0; j < 8; ++j) {
      int o = og * 8 + j;
      float acc = bsrc[o];
      const float* wrow = wsrc + o * 64;
#pragma unroll
      for (int c = 0; c < 64; ++c) acc += wrow[c] * xr[c];
      v8[j] = f2bf(acc * kscale);
    }
    *(bf16x8*)outp = v8;
  }
}

// ---------------- Kernel B: MFMA flash attention (exact R18: dbuf, 1 barrier) ----------------
// grid (72, 2, NSPLIT) x 256. 128 q/block, 32 q/wave.
#define LDPK 80
#define LDP  72
__global__ __launch_bounds__(256) void k_attn(
    const short* __restrict__ Qg, const short* __restrict__ Kg, const short* __restrict__ Vgt,
    u32* __restrict__ PoT, float* __restrict__ Pl) {
  __shared__ __align__(16) short Kt[2][64 * LDPK];
  __shared__ __align__(16) short Vt[2][64 * LDP];
  int b = blockIdx.y;
  int n0 = blockIdx.x * 128;
  int ks = blockIdx.z;
  int tid = threadIdx.x;
  int w = tid >> 6, lane = tid & 63;
  int L = lane & 15, quad = lane >> 4;

  bf16x8 qa[2][2];
#pragma unroll
  for (int qt = 0; qt < 2; ++qt) {
    const short* qb_ = Qg + ((size_t)(b * NPOS + n0 + w * 32 + qt * 16 + L)) * 64;
    qa[qt][0] = *(const bf16x8*)(qb_ + quad * 8);
    qa[qt][1] = *(const bf16x8*)(qb_ + 32 + quad * 8);
  }

  f32x4 o[2][4];
#pragma unroll
  for (int qt = 0; qt < 2; ++qt)
#pragma unroll
    for (int nb = 0; nb < 4; ++nb) o[qt][nb] = (f32x4){0.f, 0.f, 0.f, 0.f};
  float rl[2] = {0.f, 0.f};

  int c8 = tid & 7, dr = tid >> 3;
  i32x4 kr0, kr1, vr0, vr1;
  {
    int kt = ks * TILES_PER_SPLIT;
    const i32x4* src = (const i32x4*)(Kg + ((size_t)(b * NPOS + kt * 64)) * 64);
    kr0 = src[tid]; kr1 = src[tid + 256];
    const short* vbase = Vgt + (size_t)b * NPOS + kt * 64 + c8 * 8;
    vr0 = *(const i32x4*)(vbase + (size_t)dr * NTOT);
    vr1 = *(const i32x4*)(vbase + (size_t)(dr + 32) * NTOT);
    i32x4* dst = (i32x4*)Kt[0];
    dst[(tid >> 3) * 10 + (tid & 7)] = kr0;
    dst[((tid + 256) >> 3) * 10 + (tid & 7)] = kr1;
    i32x4* vdst = (i32x4*)Vt[0];
    vdst[dr * 9 + c8] = vr0;
    vdst[(dr + 32) * 9 + c8] = vr1;
  }

  for (int t = 0; t < TILES_PER_SPLIT; ++t) {
    int cur = t & 1;
    if (t + 1 < TILES_PER_SPLIT) {
      int kt = ks * TILES_PER_SPLIT + t + 1;
      const i32x4* src = (const i32x4*)(Kg + ((size_t)(b * NPOS + kt * 64)) * 64);
      kr0 = src[tid]; kr1 = src[tid + 256];
      const short* vbase = Vgt + (size_t)b * NPOS + kt * 64 + c8 * 8;
      vr0 = *(const i32x4*)(vbase + (size_t)dr * NTOT);
      vr1 = *(const i32x4*)(vbase + (size_t)(dr + 32) * NTOT);
    }
    __syncthreads();

    const i32x4* kt4 = (const i32x4*)Kt[cur];
    const short* vt = Vt[cur];
#pragma unroll
    for (int kti = 0; kti < 4; ++kti) {
      bf16x8 kf0 = __builtin_bit_cast(bf16x8, kt4[(kti * 16 + L) * 10 + quad]);
      bf16x8 kf1 = __builtin_bit_cast(bf16x8, kt4[(kti * 16 + L) * 10 + 4 + quad]);
      bf16x4 pp[2];
#pragma unroll
      for (int qt = 0; qt < 2; ++qt) {
        f32x4 st = {0.f, 0.f, 0.f, 0.f};
        st = __builtin_amdgcn_mfma_f32_16x16x32_bf16(kf0, qa[qt][0], st, 0, 0, 0);
        st = __builtin_amdgcn_mfma_f32_16x16x32_bf16(kf1, qa[qt][1], st, 0, 0, 0);
        float p0 = __builtin_amdgcn_exp2f(st[0]);
        float p1 = __builtin_amdgcn_exp2f(st[1]);
        float p2 = __builtin_amdgcn_exp2f(st[2]);
        float p3 = __builtin_amdgcn_exp2f(st[3]);
        rl[qt] += (p0 + p1) + (p2 + p3);
        u32 lo = __builtin_amdgcn_perm(__builtin_bit_cast(u32, p1), __builtin_bit_cast(u32, p0), 0x07060302u);
        u32 hi = __builtin_amdgcn_perm(__builtin_bit_cast(u32, p3), __builtin_bit_cast(u32, p2), 0x07060302u);
        u32 pr[2] = {lo, hi};
        pp[qt] = __builtin_bit_cast(bf16x4, pr);
      }
#pragma unroll
      for (int nb = 0; nb < 4; ++nb) {
        bf16x4 va = *(const bf16x4*)(vt + (nb * 16 + L) * LDP + kti * 16 + quad * 4);
#pragma unroll
        for (int qt = 0; qt < 2; ++qt)
          o[qt][nb] = __builtin_amdgcn_mfma_f32_16x16x16bf16_1k(va, pp[qt], o[qt][nb], 0, 0, 0);
      }
    }

    if (t + 1 < TILES_PER_SPLIT) {
      int nxt = 1 - cur;
      i32x4* dst = (i32x4*)Kt[nxt];
      dst[(tid >> 3) * 10 + (tid & 7)] = kr0;
      dst[((tid + 256) >> 3) * 10 + (tid & 7)] = kr1;
      i32x4* vdst = (i32x4*)Vt[nxt];
      vdst[dr * 9 + c8] = vr0;
      vdst[(dr + 32) * 9 + c8] = vr1;
    }
  }

#pragma unroll
  for (int qt = 0; qt < 2; ++qt) {
    rl[qt] += __shfl_xor(rl[qt], 16);
    rl[qt] += __shfl_xor(rl[qt], 32);
  }

#pragma unroll
  for (int qt = 0; qt < 2; ++qt) {
    int qg = b * NPOS + n0 + w * 32 + qt * 16 + L;
#pragma unroll
    for (int nb = 0; nb < 4; ++nb)
#pragma unroll
      for (int ip = 0; ip < 2; ++ip) {
        u32 pk = ((u32)(unsigned short)f2bf(o[qt][nb][2 * ip + 1]) << 16) |
                 (u32)(unsigned short)f2bf(o[qt][nb][2 * ip]);
        int d32 = nb * 8 + quad * 2 + ip;
        PoT[((size_t)(ks * 32 + d32)) * NTOT + qg] = pk;
      }
    if (quad == 0) Pl[(size_t)ks * NTOT + qg] = rl[qt];
  }
}

// ---------------- Kernel C: merge + residual + LN2 + MFMA proj_in (+X2) ----------------
// grid (288) x 256 (exact R13).
__global__ __launch_bounds__(256) void k_res_ln2_proj(
    const float* __restrict__ x, const u32* __restrict__ PoT, const float* __restrict__ Pl,
    const float* __restrict__ ln2w, const float* __restrict__ ln2b,
    const float* __restrict__ piw,
    float* __restrict__ X2, float* __restrict__ Hbuf) {
  __shared__ float s1a[4 * 64], s2a[4 * 64];
  __shared__ __align__(16) short xn[64 * 72];
  int t = threadIdx.x;
  int w = t >> 6;
  int p = t & 63;
  int q0 = blockIdx.x * 64;
  int q = q0 + p;
  int b = q / NPOS;
  int nn = q0 % NPOS;
  int n = q % NPOS;

  float lsum = 0.f;
#pragma unroll
  for (int s = 0; s < NSPLIT; ++s) lsum += Pl[(size_t)s * NTOT + q];
  float inv = 1.f / lsum;

  const float* xb = x + (size_t)b * CH * NPOS + n;
  float xr[16];
  float s1 = 0.f, s2 = 0.f;
#pragma unroll
  for (int j2 = 0; j2 < 8; ++j2) {
    float a0 = 0.f, a1 = 0.f;
#pragma unroll
    for (int s = 0; s < NSPLIT; ++s) {
      u32 v = PoT[((size_t)(s * 32 + w * 8 + j2)) * NTOT + q];
      a0 += __builtin_bit_cast(float, v << 16);
      a1 += __builtin_bit_cast(float, v & 0xffff0000u);
    }
    int cl = 2 * j2;
    int c = w * 16 + cl;
    float v0 = xb[(size_t)c * NPOS] + a0 * inv;
    float v1 = xb[(size_t)(c + 1) * NPOS] + a1 * inv;
    xr[cl] = v0; xr[cl + 1] = v1;
    s1 += v0 + v1;
    s2 += v0 * v0 + v1 * v1;
  }
  s1a[w * 64 + p] = s1;
  s2a[w * 64 + p] = s2;
  {
    float* xo = X2 + (size_t)b * CH * NPOS + n;
#pragma unroll
    for (int cl = 0; cl < 16; ++cl) xo[(size_t)(w * 16 + cl) * NPOS] = xr[cl];
  }
  __syncthreads();
  float mu = 0.f, m2 = 0.f;
#pragma unroll
  for (int ww = 0; ww < 4; ++ww) { mu += s1a[ww * 64 + p]; m2 += s2a[ww * 64 + p]; }
  mu *= (1.f / 64.f);
  float var = m2 * (1.f / 64.f) - mu * mu;
  float rstd = rsqrtf(var + 1e-5f);
  {
    u32* xw = (u32*)xn;
#pragma unroll
    for (int j2 = 0; j2 < 8; ++j2) {
      int cl = 2 * j2, c = w * 16 + cl;
      float y0 = (xr[cl] - mu) * rstd * ln2w[c] + ln2b[c];
      float y1 = (xr[cl + 1] - mu) * rstd * ln2w[c + 1] + ln2b[c + 1];
      u32 pk = ((u32)(unsigned short)f2bf(y1) << 16) | (u32)(unsigned short)f2bf(y0);
      xw[p * 36 + w * 8 + j2] = pk;
    }
  }
  __syncthreads();
  int lane = t & 63;
  int L = lane & 15, quad = lane >> 4;
  bf16x8 a0, a1;
  {
    const float* wr = piw + (w * 16 + L) * 64 + quad * 8;
#pragma unroll
    for (int j = 0; j < 8; ++j) { a0[j] = f2bf(wr[j]); a1[j] = f2bf(wr[32 + j]); }
  }
  float* hb = Hbuf + (size_t)b * CH * NPOS + nn;
#pragma unroll
  for (int pt = 0; pt < 4; ++pt) {
    bf16x8 b0 = *(const bf16x8*)(xn + (pt * 16 + L) * 72 + quad * 8);
    bf16x8 b1 = *(const bf16x8*)(xn + (pt * 16 + L) * 72 + 32 + quad * 8);
    f32x4 acc = {0.f, 0.f, 0.f, 0.f};
    acc = __builtin_amdgcn_mfma_f32_16x16x32_bf16(a0, b0, acc, 0, 0, 0);
    acc = __builtin_amdgcn_mfma_f32_16x16x32_bf16(a1, b1, acc, 0, 0, 0);
#pragma unroll
    for (int i = 0; i < 4; ++i)
      hb[(size_t)(w * 16 + quad * 4 + i) * NPOS + pt * 16 + L] = acc[i];
  }
}

// ---------------- Kernel D: per-patch spectral filter, lane-cooperative ----------------
// grid (576) x 256. Wave handles 8 patch-channels; lane = p*8 + g (p = row/freq,
// g = patch-in-group). Cross-stage transposes via __shfl within stride-8 groups.
// Dynamic twiddles via incremental rotation (angle 2*pi*p/8).
__global__ __launch_bounds__(256) void k_fft(float* __restrict__ Hbuf, const float* __restrict__ fftw) {
  int tid = threadIdx.x;
  int wv = tid >> 6, lane = tid & 63;
  int p = lane >> 3, g = lane & 7;
  int widx = blockIdx.x * 4 + wv;        // 0..2303
  int bc = widx / 18;                    // (b,c)
  int grp = widx % 18;
  int b = bc >> 6, c = bc & 63;
  int pidx = grp * 8 + g;                // 0..143
  int hb = pidx / 12, wb = pidx % 12;
  float* base = Hbuf + (size_t)(b * CH + c) * NPOS + (hb * 8 + p) * 96 + wb * 8;
  const float r = 0.70710678118654752440f;
  const float CO[8] = {1.f, r, 0.f, -r, -1.f, -r, 0.f, r};
  const float SI[8] = {0.f, r, 1.f, r, 0.f, -r, -1.f, -r};
  f32x4 ra = *(const f32x4*)(base);
  f32x4 rb = *(const f32x4*)(base + 4);
  float row[8] = {ra[0], ra[1], ra[2], ra[3], rb[0], rb[1], rb[2], rb[3]};
  // stage 1: row rfft (static twiddles)
  float A1r[5], A1i[5];
#pragma unroll
  for (int v = 0; v < 5; ++v) {
    float sr = 0.f, si = 0.f;
#pragma unroll
    for (int q = 0; q < 8; ++q) {
      int k = (q * v) & 7;
      sr += row[q] * CO[k];
      si -= row[q] * SI[k];
    }
    A1r[v] = sr; A1i[v] = si;
  }
  // per-lane rotation step: angle 2*pi*p/8 (lane doubles as u in stage 2)
  float ang = (float)p * 0.78539816339744831f;
  float cu = __cosf(ang), su = __sinf(ang);
  // stage 2: forward column DFT at u=p + filter
  float Br[5], Bi[5];
#pragma unroll
  for (int v = 0; v < 5; ++v) {
    float br = 0.f, bi = 0.f, cr = 1.f, ci = 0.f;
#pragma unroll
    for (int j = 0; j < 8; ++j) {
      float a  = __shfl(A1r[v], j * 8 + g, 64);
      float ai = __shfl(A1i[v], j * 8 + g, 64);
      br += a * cr + ai * ci;
      bi += ai * cr - a * ci;
      float ncr = cr * cu - ci * su;
      float nci = ci * cu + cr * su;
      cr = ncr; ci = nci;
    }
    float wvv = fftw[c * 40 + p * 5 + v];
    Br[v] = br * wvv; Bi[v] = bi * wvv;
  }
  // stage 2b: inverse column DFT at row p
  float A2r[5], A2i[5];
#pragma unroll
  for (int v = 0; v < 5; ++v) {
    float yr = 0.f, yi = 0.f, cr = 1.f, ci = 0.f;
#pragma unroll
    for (int u = 0; u < 8; ++u) {
      float bR = __shfl(Br[v], u * 8 + g, 64);
      float bI = __shfl(Bi[v], u * 8 + g, 64);
      yr += bR * cr - bI * ci;
      yi += bI * cr + bR * ci;
      float ncr = cr * cu - ci * su;
      float nci = ci * cu + cr * su;
      cr = ncr; ci = nci;
    }
    A2r[v] = yr * 0.125f; A2i[v] = yi * 0.125f;
  }
  // stage 3: inverse row rfft (static twiddles)
  float outv[8];
#pragma unroll
  for (int q = 0; q < 8; ++q) {
    float acc = A2r[0] + ((q & 1) ? -A2r[4] : A2r[4]);
#pragma unroll
    for (int v = 1; v < 4; ++v) {
      int k = (q * v) & 7;
      acc += 2.f * (A2r[v] * CO[k] - A2i[v] * SI[k]);
    }
    outv[q] = acc * 0.125f;
  }
  f32x4 wa = {outv[0], outv[1], outv[2], outv[3]};
  f32x4 wb2 = {outv[4], outv[5], outv[6], outv[7]};
  *(f32x4*)(base) = wa;
  *(f32x4*)(base + 4) = wb2;
}

// ---------------- Kernel E1: dwconv3x3 + gelu-gate -> G ----------------
// grid (72, 32) x 256.
__global__ __launch_bounds__(256) void k_dw_gate(
    const float* __restrict__ Hbuf, const float* __restrict__ dww,
    float* __restrict__ G) {
  int cc = blockIdx.y;
  int q = blockIdx.x * 256 + threadIdx.x;
  int b = q / NPOS, n = q % NPOS;
  int y = n / 96, xx = n % 96;
  const float* h1 = Hbuf + (size_t)(b * CH + cc) * NPOS;
  const float* h2 = Hbuf + (size_t)(b * CH + cc + 32) * NPOS;
  float wd1[9], wd2[9];
#pragma unroll
  for (int ki = 0; ki < 9; ++ki) { wd1[ki] = dww[cc * 9 + ki]; wd2[ki] = dww[(cc + 32) * 9 + ki]; }
  float d1 = 0.f, d2 = 0.f;
  for (int dy = -1; dy <= 1; ++dy) {
    int yy = y + dy;
    if (yy < 0 || yy >= 96) continue;
    for (int dx = -1; dx <= 1; ++dx) {
      int xv = xx + dx;
      if (xv < 0 || xv >= 96) continue;
      int ki = (dy + 1) * 3 + (dx + 1);
      d1 += h1[yy * 96 + xv] * wd1[ki];
      d2 += h2[yy * 96 + xv] * wd2[ki];
    }
  }
  G[(size_t)cc * NTOT + q] = gelu_exact(d1) * d2;
}

// ---------------- Kernel E2: proj_out + residual ----------------
// grid (72, 8) x 256.
__global__ __launch_bounds__(256) void k_proj_out(
    const float* __restrict__ G, const float* __restrict__ poww,
    const float* __restrict__ X2, float* __restrict__ out) {
  int og = blockIdx.y;
  int q = blockIdx.x * 256 + threadIdx.x;
  int b = q / NPOS, n = q % NPOS;
  float g[32];
#pragma unroll
  for (int cg = 0; cg < 32; ++cg) g[cg] = G[(size_t)cg * NTOT + q];
  const float* xr = X2 + (size_t)b * CH * NPOS + n;
  float* ob = out + (size_t)b * CH * NPOS + n;
#pragma unroll
  for (int j = 0; j < 8; ++j) {
    int oc = og * 8 + j;
    const float* prow = poww + oc * 32;
    float acc = xr[(size_t)oc * NPOS];
#pragma unroll
    for (int cg = 0; cg < 32; ++cg) acc += prow[cg] * g[cg];
    ob[(size_t)oc * NPOS] = acc;
  }
}

extern "C" void kernel_launch(void* const* d_in, const int* in_sizes, int n_in,
                              void* d_out, int out_size, void* d_ws, size_t ws_size,
                              hipStream_t stream) {
  const float* x    = (const float*)d_in[0];
  const float* ln1w = (const float*)d_in[1];
  const float* ln1b = (const float*)d_in[2];
  const float* ln2w = (const float*)d_in[3];
  const float* ln2b = (const float*)d_in[4];
  const float* qw   = (const float*)d_in[5];
  const float* qb   = (const float*)d_in[6];
  const float* kw   = (const float*)d_in[7];
  const float* kb   = (const float*)d_in[8];
  const float* vw   = (const float*)d_in[9];
  const float* vb   = (const float*)d_in[10];
  const float* fftw = (const float*)d_in[11];
  const float* piw  = (const float*)d_in[12];
  const float* dww  = (const float*)d_in[13];
  const float* poww = (const float*)d_in[14];

  short* Qg  = (short*)d_ws;
  short* Kg  = Qg + (size_t)NTOT * 64;
  short* Vgt = Kg + (size_t)NTOT * 64;
  u32*   PoT = (u32*)(Vgt + (size_t)NTOT * 64);
  float* Pl  = (float*)(PoT + (size_t)NSPLIT * 32 * NTOT);
  float* X2  = Pl + (size_t)NSPLIT * NTOT;
  float* Hbuf = X2 + (size_t)NTOT * 64;
  float* G   = Hbuf + (size_t)NTOT * 64;

  k_ln_qkv<<<dim3(72, 3, 8), 256, 0, stream>>>(x, ln1w, ln1b, qw, qb, kw, kb, vw, vb, Qg, Kg, Vgt);
  k_attn<<<dim3(72, 2, NSPLIT), 256, 0, stream>>>(Qg, Kg, Vgt, PoT, Pl);
  k_res_ln2_proj<<<dim3(288), 256, 0, stream>>>(x, PoT, Pl, ln2w, ln2b, piw, X2, Hbuf);
  k_fft<<<dim3(576), 256, 0, stream>>>(Hbuf, fftw);
  k_dw_gate<<<dim3(72, 32), 256, 0, stream>>>(Hbuf, dww, G);
  k_proj_out<<<dim3(72, 8), 256, 0, stream>>>(G, poww, X2, (float*)d_out);
}